// Round 1
// baseline (304.014 us; speedup 1.0000x reference)
//
#include <hip/hip_runtime.h>
#include <math.h>

// Top-1 MoE, 6-dispatch pipeline.
//   memset -> prep -> gate_partial -> gate_finalize -> gemm1 -> gemm2+cheap.
// r13: cheap-expert dot products (23 rows: p2_w, p4_w, rg_u, fl_dw cols) are
// computed by gate_partial's n-tile-0 blocks as an extra 64-col MFMA tile
// (B read direct from L2, split hi/lo like the gate => f32-accurate).
// gate_finalize turns the dots into per-token gate scalars (gvec); the cheap
// blocks in gemm2_cheap become pure streaming (no shfl chains / syncthreads),
// which were the latency bottleneck (59us @ 3.4% MFMA / 21% VALU / 15% HBM).
// cdot partials live in d_out (dead until gemm2 overwrites all rows).

#define E 1024
#define GH 256
#define NEXP 6
#define NTOK 8192
#define NCH 24   // cheap-dot cols: 2 p2 + 4 p4 + 1 rg + 16 film + 1 pad

typedef __attribute__((ext_vector_type(8))) short bf16x8;
typedef __attribute__((ext_vector_type(4))) float f32x4;

__device__ __forceinline__ float gelu_erf(float v) {
    return 0.5f * v * (1.0f + erff(v * 0.70710678118654752440f));
}

__device__ __forceinline__ unsigned short f2bf(float f) {
    union { float f; unsigned u; } c; c.f = f;
    unsigned u = c.u;
    u += 0x7fffu + ((u >> 16) & 1u);   // RNE
    return (unsigned short)(u >> 16);
}

__device__ __forceinline__ float bf2f(unsigned short h) {
    union { unsigned u; float f; } c; c.u = ((unsigned)h) << 16;
    return c.f;
}

// LDS tile addressing (ushort units): row stride 32 (=64B), k-group XOR swizzle.
__device__ __forceinline__ int ldso(int row, int q) {
    return row * 32 + ((q ^ ((row >> 1) & 3)) << 3);
}

// ---------------- prep: convert + all transposes, one kernel ----------------
__global__ __launch_bounds__(256)
void prep_kernel(const float* __restrict__ x, unsigned short* __restrict__ xh,
                 unsigned short* __restrict__ xl,
                 const float* __restrict__ gw1, unsigned short* __restrict__ w1cat,
                 const float* __restrict__ p2_w, const float* __restrict__ p4_w,
                 const float* __restrict__ rg_u, const float* __restrict__ fl_dw,
                 unsigned short* __restrict__ w1cheap,
                 const float* __restrict__ dfc_w, unsigned short* __restrict__ dfc_wt,
                 const float* __restrict__ dproj_w, unsigned short* __restrict__ dpj_wt,
                 const float* __restrict__ sfc_w, unsigned short* __restrict__ sfc_wt,
                 const float* __restrict__ sproj_w, unsigned short* __restrict__ spj_wt) {
    __shared__ float tile[32][33];
    const int tid = threadIdx.x;
    const int tx = tid & 31, ty = tid >> 5;
    int b = blockIdx.x;
    if (b < 2048) {                       // x -> x_hi + x_lo
        const int n4 = NTOK * E / 4;
        for (int i = b * 256 + tid; i < n4; i += 2048 * 256) {
            float4 v = reinterpret_cast<const float4*>(x)[i];
            ushort4 h, l;
            h.x = f2bf(v.x); l.x = f2bf(v.x - bf2f(h.x));
            h.y = f2bf(v.y); l.y = f2bf(v.y - bf2f(h.y));
            h.z = f2bf(v.z); l.z = f2bf(v.z - bf2f(h.z));
            h.w = f2bf(v.w); l.w = f2bf(v.w - bf2f(h.w));
            reinterpret_cast<ushort4*>(xh)[i] = h;
            reinterpret_cast<ushort4*>(xl)[i] = l;
        }
        return;
    }
    b -= 2048;
    if (b < 256) {                        // gw1 [E][GH] -> w1cat [GH][hi|lo]
        const int c0 = (b & 7) * 32, r0 = (b >> 3) * 32;
#pragma unroll
        for (int i = 0; i < 4; ++i)
            tile[ty + i * 8][tx] = gw1[(size_t)(r0 + ty + i * 8) * GH + c0 + tx];
        __syncthreads();
#pragma unroll
        for (int i = 0; i < 4; ++i) {
            float v = tile[tx][ty + i * 8];
            unsigned short h = f2bf(v);
            size_t row = (size_t)(c0 + ty + i * 8) * 2048;
            w1cat[row + r0 + tx] = h;
            w1cat[row + 1024 + r0 + tx] = f2bf(v - bf2f(h));
        }
        return;
    }
    b -= 256;
    if (b < 64) {                         // cheap-dot weights -> w1cheap [64][hi|lo]
        const int r = b;
        const int k4 = tid * 4;
        float4 v = {0.f, 0.f, 0.f, 0.f};
        if (r < 2)       v = *reinterpret_cast<const float4*>(&p2_w[r * E + k4]);
        else if (r < 6)  v = *reinterpret_cast<const float4*>(&p4_w[(r - 2) * E + k4]);
        else if (r == 6) v = *reinterpret_cast<const float4*>(&rg_u[k4]);
        else if (r < 23) {
            const int j = r - 7;          // fl_dw is [E][16]: gather column j
            v.x = fl_dw[(k4 + 0) * 16 + j];
            v.y = fl_dw[(k4 + 1) * 16 + j];
            v.z = fl_dw[(k4 + 2) * 16 + j];
            v.w = fl_dw[(k4 + 3) * 16 + j];
        }
        ushort4 h, l;
        h.x = f2bf(v.x); l.x = f2bf(v.x - bf2f(h.x));
        h.y = f2bf(v.y); l.y = f2bf(v.y - bf2f(h.y));
        h.z = f2bf(v.z); l.z = f2bf(v.z - bf2f(h.z));
        h.w = f2bf(v.w); l.w = f2bf(v.w - bf2f(h.w));
        *reinterpret_cast<ushort4*>(&w1cheap[r * 2048 + k4]) = h;
        *reinterpret_cast<ushort4*>(&w1cheap[r * 2048 + 1024 + k4]) = l;
        return;
    }
    b -= 64;
    const float* src; unsigned short* dst; int R, C, nbx;
    if (b < 2048)      { src = dfc_w;   dst = dfc_wt; R = 1024; C = 2048; nbx = 64; }
    else if (b < 4096) { src = dproj_w; dst = dpj_wt; R = 2048; C = 1024; nbx = 32; b -= 2048; }
    else if (b < 5120) { src = sfc_w;   dst = sfc_wt; R = 1024; C = 1024; nbx = 32; b -= 4096; }
    else               { src = sproj_w; dst = spj_wt; R = 1024; C = 1024; nbx = 32; b -= 5120; }
    const int c0 = (b % nbx) * 32, r0 = (b / nbx) * 32;
#pragma unroll
    for (int i = 0; i < 4; ++i)
        tile[ty + i * 8][tx] = src[(size_t)(r0 + ty + i * 8) * C + c0 + tx];
    __syncthreads();
#pragma unroll
    for (int i = 0; i < 4; ++i)
        dst[(size_t)(c0 + ty + i * 8) * R + r0 + tx] = f2bf(tile[tx][ty + i * 8]);
}

// ------ gate partial GEMM: hp_z = A_z @ w1cat, 64x64 tiles, LDS dbuf -------
// Grid (GH/64=4, NTOK/64=128, 2) = 1024 blocks. 4 waves of 32x32.
// n-tile-0 blocks additionally compute the 64x24 cheap-dot tile (A @ w1cheap^T)
// with cheap-B fragments loaded straight from L2 (256KB, fully cached).
__global__ __launch_bounds__(256)
void gate_partial_kernel(const unsigned short* __restrict__ xh,
                         const unsigned short* __restrict__ xl,
                         const unsigned short* __restrict__ w1cat,
                         const unsigned short* __restrict__ w1cheap,
                         float* __restrict__ hp0, float* __restrict__ hp1,
                         float* __restrict__ cdot0, float* __restrict__ cdot1) {
    __shared__ __align__(16) unsigned short As[2][64 * 32];
    __shared__ __align__(16) unsigned short Bs[2][64 * 32];
    const int tid = threadIdx.x;
    const int t0 = blockIdx.y * 64, n0 = blockIdx.x * 64, z = blockIdx.z;
    const unsigned short* A = z ? xl : xh;
    float* hp = z ? hp1 : hp0;
    float* cd = z ? cdot1 : cdot0;

    const int lane = tid & 63, wv = tid >> 6;
    const int wm = (wv & 1) * 32, wn = (wv >> 1) * 32;
    const int lm = lane & 15, q = lane >> 4;
    const int r0 = tid >> 2, gsl = tid & 3;
    const int g = gsl ^ ((r0 >> 1) & 3);
    const int so = r0 * 32 + gsl * 8;

    const unsigned short* pa = A + (size_t)(t0 + r0) * E + g * 8;
    const unsigned short* pb = w1cat + (size_t)(n0 + r0) * 2048 + g * 8;

    // cheap tile: wave wv covers rows wm..wm+31 x cheap-cols tc*16..tc*16+15
    const bool docheap = (blockIdx.x == 0);
    const int tc = wv >> 1;
    const unsigned short* pcw = w1cheap + (size_t)(tc * 16 + lm) * 2048 + q * 8;

    f32x4 acc[2][2];
#pragma unroll
    for (int s = 0; s < 2; ++s)
#pragma unroll
        for (int t = 0; t < 2; ++t) acc[s][t] = (f32x4){0.f, 0.f, 0.f, 0.f};
    f32x4 accC[2];
    accC[0] = (f32x4){0.f, 0.f, 0.f, 0.f};
    accC[1] = (f32x4){0.f, 0.f, 0.f, 0.f};

    bf16x8 ra = *(const bf16x8*)(pa);
    bf16x8 rb = *(const bf16x8*)(pb);
    bf16x8 cfv, cfn;
    if (docheap) cfv = *(const bf16x8*)(pcw);
    *(bf16x8*)&As[0][so] = ra;
    *(bf16x8*)&Bs[0][so] = rb;

    int cur = 0, k0 = 0;
    while (true) {
        __syncthreads();                      // buf[cur] writes + prev reads done
        const int kn = k0 + 32;
        if (kn < 2048) {
            ra = *(const bf16x8*)(pa + (kn & 1023));
            rb = *(const bf16x8*)(pb + kn);
            if (docheap) cfn = *(const bf16x8*)(pcw + kn);
        }
        bf16x8 af[2], bf[2];
#pragma unroll
        for (int s = 0; s < 2; ++s) af[s] = *(const bf16x8*)&As[cur][ldso(wm + s * 16 + lm, q)];
#pragma unroll
        for (int t = 0; t < 2; ++t) bf[t] = *(const bf16x8*)&Bs[cur][ldso(wn + t * 16 + lm, q)];
#pragma unroll
        for (int s = 0; s < 2; ++s)
#pragma unroll
            for (int t = 0; t < 2; ++t)
                acc[s][t] = __builtin_amdgcn_mfma_f32_16x16x32_bf16(af[s], bf[t], acc[s][t], 0, 0, 0);
        if (docheap) {
            accC[0] = __builtin_amdgcn_mfma_f32_16x16x32_bf16(af[0], cfv, accC[0], 0, 0, 0);
            accC[1] = __builtin_amdgcn_mfma_f32_16x16x32_bf16(af[1], cfv, accC[1], 0, 0, 0);
        }
        if (kn >= 2048) break;
        *(bf16x8*)&As[cur ^ 1][so] = ra;
        *(bf16x8*)&Bs[cur ^ 1][so] = rb;
        cfv = cfn;
        cur ^= 1; k0 = kn;
    }
#pragma unroll
    for (int s = 0; s < 2; ++s)
#pragma unroll
        for (int t = 0; t < 2; ++t)
#pragma unroll
            for (int rg = 0; rg < 4; ++rg) {
                int rl = wm + s * 16 + q * 4 + rg;
                int c  = wn + t * 16 + lm;
                hp[(size_t)(t0 + rl) * GH + n0 + c] = acc[s][t][rg];
            }
    if (docheap) {
        const int c = tc * 16 + lm;
        if (c < NCH) {
#pragma unroll
            for (int s = 0; s < 2; ++s)
#pragma unroll
                for (int rg = 0; rg < 4; ++rg) {
                    int rl = wm + s * 16 + q * 4 + rg;
                    cd[(size_t)(t0 + rl) * NCH + c] = accC[s][rg];
                }
        }
    }
}

// ------- finalize: h=gelu(hp0+hp1+gb1); logits=h@gw2; softmax/argmax --------
// Also converts summed cheap dots into per-token gate scalars gvec[NCH].
__global__ __launch_bounds__(256)
void gate_finalize_kernel(const float* __restrict__ hp0, const float* __restrict__ hp1,
                          const float* __restrict__ gb1, const float* __restrict__ gw2,
                          const float* __restrict__ gb2, const float* __restrict__ ebias,
                          const float* __restrict__ pm_alpha,
                          const float* __restrict__ cdot0, const float* __restrict__ cdot1,
                          const float* __restrict__ p2_alpha, const float* __restrict__ p2_b,
                          const float* __restrict__ p4_alpha, const float* __restrict__ p4_b,
                          const float* __restrict__ rg_b, const float* __restrict__ fl_db,
                          float* __restrict__ scale, int* __restrict__ counts,
                          int* __restrict__ tlist, int* __restrict__ eid,
                          float* __restrict__ gvec) {
    __shared__ float hs[32][264];
    __shared__ float g2s[GH * NEXP];
    __shared__ int tokexp[32];
    const int tid = threadIdx.x;
    const int t0 = blockIdx.x * 32;
    for (int i = tid; i < GH * NEXP; i += 256) g2s[i] = gw2[i];
#pragma unroll
    for (int i = 0; i < 8; ++i) {
        int f4 = i * 256 + tid;
        int row = f4 >> 6, c4 = (f4 & 63) * 4;
        size_t base = (size_t)(t0 + row) * GH + c4;
        float4 a = *reinterpret_cast<const float4*>(&hp0[base]);
        float4 b = *reinterpret_cast<const float4*>(&hp1[base]);
        float4 o;
        o.x = gelu_erf(a.x + b.x + gb1[c4 + 0]);
        o.y = gelu_erf(a.y + b.y + gb1[c4 + 1]);
        o.z = gelu_erf(a.z + b.z + gb1[c4 + 2]);
        o.w = gelu_erf(a.w + b.w + gb1[c4 + 3]);
        *reinterpret_cast<float4*>(&hs[row][c4]) = o;
    }
    __syncthreads();
    const int t = tid >> 3, j = tid & 7;
    float p[NEXP] = {0.f, 0.f, 0.f, 0.f, 0.f, 0.f};
#pragma unroll 8
    for (int kk = 0; kk < 32; ++kk) {
        int k = j + kk * 8;
        float hv = hs[t][k];
        const float* gr = &g2s[k * NEXP];
#pragma unroll
        for (int m = 0; m < NEXP; ++m) p[m] += hv * gr[m];
    }
#pragma unroll
    for (int m = 0; m < NEXP; ++m) {
        p[m] += __shfl_xor(p[m], 4, 64);
        p[m] += __shfl_xor(p[m], 2, 64);
        p[m] += __shfl_xor(p[m], 1, 64);
    }
    if (j == 0) {
        float L[NEXP];
#pragma unroll
        for (int m = 0; m < NEXP; ++m) L[m] = p[m] + gb2[m] + ebias[m];
        float mx = L[0]; int am = 0;
#pragma unroll
        for (int m = 1; m < NEXP; ++m) { if (L[m] > mx) { mx = L[m]; am = m; } }
        float S = 0.f;
#pragma unroll
        for (int m = 0; m < NEXP; ++m) S += expf(L[m] - mx);
        float pt = 1.f / S;
        scale[t0 + t] = pm_alpha[0] * (pt / (pt + 1e-9f));
        eid[t0 + t] = am;
        tokexp[t] = am;
    }
    __syncthreads();
    if (tid < NEXP) {
        const int e = tid;
        int cnt = 0;
#pragma unroll
        for (int i = 0; i < 32; ++i) cnt += (tokexp[i] == e);
        if (cnt) {
            int base = atomicAdd(&counts[e], cnt);
            int pos = 0;
#pragma unroll
            for (int i = 0; i < 32; ++i)
                if (tokexp[i] == e) tlist[e * NTOK + base + (pos++)] = t0 + i;
        }
    }
    // ---- per-token cheap-gate scalars (independent of the above) ----
    for (int i = tid; i < 32 * NCH; i += 256) {
        const int tt = i / NCH, slot = i - tt * NCH;
        const int tok = t0 + tt;
        float s = cdot0[(size_t)tok * NCH + slot] + cdot1[(size_t)tok * NCH + slot];
        float val;
        if (slot < 2)       val = p2_alpha[slot] * gelu_erf(s + p2_b[slot]);
        else if (slot < 6)  val = p4_alpha[slot - 2] * gelu_erf(s + p4_b[slot - 2]);
        else if (slot == 6) val = 1.f / (1.f + expf(-(s + rg_b[0])));
        else if (slot < 23) val = gelu_erf(s + fl_db[slot - 7]);
        else                val = 0.f;
        gvec[(size_t)tok * NCH + slot] = val;
    }
}

// ---------------- GEMM1: gather x_hi -> gelu -> packed bf16 h ---------------
// 64x64 tiles, 4 waves of 32x32, LDS double buffer.
__global__ __launch_bounds__(256)
void moe_gemm1_kernel(const unsigned short* __restrict__ xh,
                      const unsigned short* __restrict__ B0, const unsigned short* __restrict__ B1,
                      const float* __restrict__ bias0, const float* __restrict__ bias1,
                      const int* __restrict__ counts, const int* __restrict__ tlist,
                      unsigned short* __restrict__ H0, unsigned short* __restrict__ H1) {
    const int z = blockIdx.z;
    const int N = z ? 1024 : 2048;
    const int cnt = counts[z];
    const int i0 = blockIdx.y * 64;
    const int n0 = blockIdx.x * 64;
    if (i0 >= cnt || n0 >= N) return;
    const unsigned short* Bz = z ? B1 : B0;
    const float* bias = z ? bias1 : bias0;

    __shared__ __align__(16) unsigned short As[2][64 * 32];
    __shared__ __align__(16) unsigned short Bs[2][64 * 32];
    __shared__ int toks[64];
    const int tid = threadIdx.x;
    if (tid < 64) toks[tid] = tlist[z * NTOK + min(i0 + tid, cnt - 1)];
    __syncthreads();

    const int lane = tid & 63, wv = tid >> 6;
    const int wm = (wv & 1) * 32, wn = (wv >> 1) * 32;
    const int lm = lane & 15, q = lane >> 4;
    const int r0 = tid >> 2, gsl = tid & 3;
    const int g = gsl ^ ((r0 >> 1) & 3);
    const int so = r0 * 32 + gsl * 8;

    const unsigned short* pa = xh + (size_t)toks[r0] * E + g * 8;
    const unsigned short* pb = Bz + (size_t)(n0 + r0) * E + g * 8;

    f32x4 acc[2][2];
#pragma unroll
    for (int s = 0; s < 2; ++s)
#pragma unroll
        for (int t = 0; t < 2; ++t) acc[s][t] = (f32x4){0.f, 0.f, 0.f, 0.f};

    bf16x8 ra = *(const bf16x8*)(pa);
    bf16x8 rb = *(const bf16x8*)(pb);
    *(bf16x8*)&As[0][so] = ra;
    *(bf16x8*)&Bs[0][so] = rb;

    int cur = 0, k0 = 0;
    while (true) {
        __syncthreads();
        const int kn = k0 + 32;
        if (kn < E) {
            ra = *(const bf16x8*)(pa + kn);
            rb = *(const bf16x8*)(pb + kn);
        }
        bf16x8 af[2], bf[2];
#pragma unroll
        for (int s = 0; s < 2; ++s) af[s] = *(const bf16x8*)&As[cur][ldso(wm + s * 16 + lm, q)];
#pragma unroll
        for (int t = 0; t < 2; ++t) bf[t] = *(const bf16x8*)&Bs[cur][ldso(wn + t * 16 + lm, q)];
#pragma unroll
        for (int s = 0; s < 2; ++s)
#pragma unroll
            for (int t = 0; t < 2; ++t)
                acc[s][t] = __builtin_amdgcn_mfma_f32_16x16x32_bf16(af[s], bf[t], acc[s][t], 0, 0, 0);
        if (kn >= E) break;
        *(bf16x8*)&As[cur ^ 1][so] = ra;
        *(bf16x8*)&Bs[cur ^ 1][so] = rb;
        cur ^= 1; k0 = kn;
    }
    unsigned short* Hz = z ? H1 : H0;
#pragma unroll
    for (int s = 0; s < 2; ++s)
#pragma unroll
        for (int t = 0; t < 2; ++t)
#pragma unroll
            for (int rg = 0; rg < 4; ++rg) {
                int rl = wm + s * 16 + q * 4 + rg;
                int gc = n0 + wn + t * 16 + lm;
                float v = acc[s][t][rg] + bias[gc];
                Hz[(size_t)(i0 + rl) * N + gc] = f2bf(gelu_erf(v));
            }
}

// -------- fused GEMM2 (experts 0/1 down-proj) + cheap experts (2..5) --------
// blocks [0,1024): gemm2 64x64 tile, LDS dbuf.
// blocks [1024, 1024+NTOK): cheap token b-1024 -- pure streaming via gvec
// (dots precomputed by gate_partial; no reductions, no syncthreads).
__global__ __launch_bounds__(256)
void gemm2_cheap_kernel(const unsigned short* __restrict__ h1, const unsigned short* __restrict__ h2,
                        const unsigned short* __restrict__ dpj, const unsigned short* __restrict__ spj,
                        const float* __restrict__ dproj_b, const float* __restrict__ sproj_b,
                        const int* __restrict__ counts, const int* __restrict__ tlist,
                        const float* __restrict__ scale,
                        const float* __restrict__ x, const int* __restrict__ eid,
                        const float* __restrict__ gvec,
                        const float* __restrict__ p2_v, const float* __restrict__ p2_bias,
                        const float* __restrict__ p4_v, const float* __restrict__ p4_bias,
                        const float* __restrict__ rg_a, const float* __restrict__ rg_bias,
                        const float* __restrict__ fl_uw, const float* __restrict__ fl_ub,
                        float* __restrict__ out) {
    __shared__ __align__(16) char smem[2 * 64 * 32 * 2 * 2 + 64 * 4];  // 16.6 KB
    const int tid = threadIdx.x;
    const int bb = blockIdx.x;
    const int lane = tid & 63;

    if (bb < 1024) {
        const int z = bb >> 9;
        const int r = bb & 511;
        const int n0 = (r & 15) * 64;
        const int i0 = (r >> 4) * 64;
        const int K = z ? 1024 : 2048;
        const int cnt = counts[z];
        if (i0 >= cnt) return;
        const int rows = min(64, cnt - i0);
        const unsigned short* Az = z ? h2 : h1;
        const unsigned short* Bz = z ? spj : dpj;
        const float* bias = z ? sproj_b : dproj_b;

        unsigned short (*As)[64 * 32] = (unsigned short (*)[64 * 32])smem;
        unsigned short (*Bs)[64 * 32] = (unsigned short (*)[64 * 32])(smem + 2 * 64 * 32 * 2);
        int* toks = (int*)(smem + 2 * 64 * 32 * 2 * 2);
        if (tid < 64) toks[tid] = tlist[z * NTOK + min(i0 + tid, cnt - 1)];
        __syncthreads();

        const int wv = tid >> 6;
        const int wm = (wv & 1) * 32, wn = (wv >> 1) * 32;
        const int lm = lane & 15, q = lane >> 4;
        const int r0 = tid >> 2, gsl = tid & 3;
        const int g = gsl ^ ((r0 >> 1) & 3);
        const int so = r0 * 32 + gsl * 8;

        const unsigned short* pa = Az + (size_t)(i0 + r0) * K + g * 8;
        const unsigned short* pb = Bz + (size_t)(n0 + r0) * K + g * 8;

        f32x4 acc[2][2];
#pragma unroll
        for (int s = 0; s < 2; ++s)
#pragma unroll
            for (int t = 0; t < 2; ++t) acc[s][t] = (f32x4){0.f, 0.f, 0.f, 0.f};

        bf16x8 ra = *(const bf16x8*)(pa);
        bf16x8 rb = *(const bf16x8*)(pb);
        *(bf16x8*)&As[0][so] = ra;
        *(bf16x8*)&Bs[0][so] = rb;

        int cur = 0, k0 = 0;
        while (true) {
            __syncthreads();
            const int kn = k0 + 32;
            if (kn < K) {
                ra = *(const bf16x8*)(pa + kn);
                rb = *(const bf16x8*)(pb + kn);
            }
            bf16x8 af[2], bf[2];
#pragma unroll
            for (int s = 0; s < 2; ++s) af[s] = *(const bf16x8*)&As[cur][ldso(wm + s * 16 + lm, q)];
#pragma unroll
            for (int t = 0; t < 2; ++t) bf[t] = *(const bf16x8*)&Bs[cur][ldso(wn + t * 16 + lm, q)];
#pragma unroll
            for (int s = 0; s < 2; ++s)
#pragma unroll
                for (int t = 0; t < 2; ++t)
                    acc[s][t] = __builtin_amdgcn_mfma_f32_16x16x32_bf16(af[s], bf[t], acc[s][t], 0, 0, 0);
            if (kn >= K) break;
            *(bf16x8*)&As[cur ^ 1][so] = ra;
            *(bf16x8*)&Bs[cur ^ 1][so] = rb;
            cur ^= 1; k0 = kn;
        }
#pragma unroll
        for (int s = 0; s < 2; ++s)
#pragma unroll
            for (int t = 0; t < 2; ++t)
#pragma unroll
                for (int rg = 0; rg < 4; ++rg) {
                    int rl = wm + s * 16 + q * 4 + rg;
                    if (rl < rows) {
                        int gc = n0 + wn + t * 16 + lm;
                        int tok = toks[rl];
                        out[(size_t)tok * E + gc] = scale[tok] * (acc[s][t][rg] + bias[gc]);
                    }
                }
        return;
    }

    // ---- cheap experts: one block per token, pure streaming via gvec ----
    const int tok = bb - 1024;
    const int e = eid[tok];
    if (e < 2) return;
    const float sc = scale[tok];
    const int k4 = tid * 4;
    const float* gv = &gvec[(size_t)tok * NCH];
    float4 o;

    if (e == 2) {
        const float g0 = gv[0], g1 = gv[1];
        float4 b0 = *reinterpret_cast<const float4*>(&p2_bias[k4]);
        float4 v0 = *reinterpret_cast<const float4*>(&p2_v[k4]);
        float4 v1 = *reinterpret_cast<const float4*>(&p2_v[E + k4]);
        o.x = b0.x + g0 * v0.x + g1 * v1.x;
        o.y = b0.y + g0 * v0.y + g1 * v1.y;
        o.z = b0.z + g0 * v0.z + g1 * v1.z;
        o.w = b0.w + g0 * v0.w + g1 * v1.w;
    } else if (e == 3) {
        o = *reinterpret_cast<const float4*>(&p4_bias[k4]);
#pragma unroll
        for (int j = 0; j < 4; ++j) {
            const float gj = gv[2 + j];
            float4 vv = *reinterpret_cast<const float4*>(&p4_v[j * E + k4]);
            o.x += gj * vv.x; o.y += gj * vv.y; o.z += gj * vv.z; o.w += gj * vv.w;
        }
    } else if (e == 4) {
        const float sg = gv[6];
        float4 xv = *reinterpret_cast<const float4*>(&x[(size_t)tok * E + k4]);
        float4 av = *reinterpret_cast<const float4*>(&rg_a[k4]);
        float4 bv = *reinterpret_cast<const float4*>(&rg_bias[k4]);
        o.x = sg * xv.x * av.x + bv.x;
        o.y = sg * xv.y * av.y + bv.y;
        o.z = sg * xv.z * av.z + bv.z;
        o.w = sg * xv.w * av.w + bv.w;
    } else {  // FiLM
        float4 xv = *reinterpret_cast<const float4*>(&x[(size_t)tok * E + k4]);
        float4 ga = *reinterpret_cast<const float4*>(&fl_ub[k4]);
        float4 be = *reinterpret_cast<const float4*>(&fl_ub[E + k4]);
#pragma unroll
        for (int j = 0; j < 16; ++j) {
            const float tj = gv[7 + j];
            float4 ug = *reinterpret_cast<const float4*>(&fl_uw[(size_t)j * 2 * E + k4]);
            float4 ub = *reinterpret_cast<const float4*>(&fl_uw[(size_t)j * 2 * E + E + k4]);
            ga.x += tj * ug.x; ga.y += tj * ug.y; ga.z += tj * ug.z; ga.w += tj * ug.w;
            be.x += tj * ub.x; be.y += tj * ub.y; be.z += tj * ub.z; be.w += tj * ub.w;
        }
        o.x = ga.x * xv.x + be.x;
        o.y = ga.y * xv.y + be.y;
        o.z = ga.z * xv.z + be.z;
        o.w = ga.w * xv.w + be.w;
    }
    o.x *= sc; o.y *= sc; o.z *= sc; o.w *= sc;
    *reinterpret_cast<float4*>(&out[(size_t)tok * E + k4]) = o;
}

extern "C" void kernel_launch(void* const* d_in, const int* in_sizes, int n_in,
                              void* d_out, int out_size, void* d_ws, size_t ws_size,
                              hipStream_t stream) {
    const float* x        = (const float*)d_in[0];
    const float* gw1      = (const float*)d_in[1];
    const float* gb1      = (const float*)d_in[2];
    const float* gw2      = (const float*)d_in[3];
    const float* gb2      = (const float*)d_in[4];
    const float* ebias    = (const float*)d_in[5];
    const float* pm_alpha = (const float*)d_in[6];
    const float* dfc_w    = (const float*)d_in[7];
    const float* dfc_b    = (const float*)d_in[8];
    const float* dproj_w  = (const float*)d_in[9];
    const float* dproj_b  = (const float*)d_in[10];
    const float* sfc_w    = (const float*)d_in[11];
    const float* sfc_b    = (const float*)d_in[12];
    const float* sproj_w  = (const float*)d_in[13];
    const float* sproj_b  = (const float*)d_in[14];
    const float* p2_w     = (const float*)d_in[15];
    const float* p2_v     = (const float*)d_in[16];
    const float* p2_alpha = (const float*)d_in[17];
    const float* p2_b     = (const float*)d_in[18];
    const float* p2_bias  = (const float*)d_in[19];
    const float* p4_w     = (const float*)d_in[20];
    const float* p4_v     = (const float*)d_in[21];
    const float* p4_alpha = (const float*)d_in[22];
    const float* p4_b     = (const float*)d_in[23];
    const float* p4_bias  = (const float*)d_in[24];
    const float* rg_u     = (const float*)d_in[25];
    const float* rg_a     = (const float*)d_in[26];
    const float* rg_b     = (const float*)d_in[27];
    const float* rg_bias  = (const float*)d_in[28];
    const float* fl_dw    = (const float*)d_in[29];
    const float* fl_db    = (const float*)d_in[30];
    const float* fl_uw    = (const float*)d_in[31];
    const float* fl_ub    = (const float*)d_in[32];
    float* out = (float*)d_out;

    char* ws = (char*)d_ws;
    size_t off = 0;
    int*            counts = (int*)(ws + off);            off += 256;
    float*          scale  = (float*)(ws + off);          off += (size_t)NTOK * 4;
    int*            tlist  = (int*)(ws + off);            off += (size_t)NEXP * NTOK * 4;
    int*            eid    = (int*)(ws + off);            off += (size_t)NTOK * 4;
    float*          gvec   = (float*)(ws + off);          off += (size_t)NTOK * NCH * 4;
    unsigned short* w1cheap= (unsigned short*)(ws + off); off += (size_t)64 * 2048 * 2;
    unsigned short* w1cat  = (unsigned short*)(ws + off); off += (size_t)GH * 2048 * 2;
    unsigned short* dfc_wt = (unsigned short*)(ws + off); off += (size_t)2048 * 1024 * 2;
    unsigned short* dpj_wt = (unsigned short*)(ws + off); off += (size_t)1024 * 2048 * 2;
    unsigned short* sfc_wt = (unsigned short*)(ws + off); off += (size_t)1024 * 1024 * 2;
    unsigned short* spj_wt = (unsigned short*)(ws + off); off += (size_t)1024 * 1024 * 2;
    unsigned short* x_hi   = (unsigned short*)(ws + off); off += (size_t)NTOK * E * 2;
    // Union region (32 MB): gate phase {x_lo, hp0, hp1} then expert phase {h1, h2}
    char* U = ws + off;
    unsigned short* x_lo = (unsigned short*)U;                              // 16 MB
    float*          hp0  = (float*)(U + (size_t)16 * 1024 * 1024);          // 8 MB
    float*          hp1  = (float*)(U + (size_t)24 * 1024 * 1024);          // 8 MB
    unsigned short* h1   = (unsigned short*)U;                              // 16 MB (2048 x 2048)
    unsigned short* h2   = (unsigned short*)(U + (size_t)16 * 1024 * 1024); // 8 MB (2048 x 1024)
    // cheap-dot partials live in d_out (dead until gemm2_cheap rewrites it)
    float* cdot0 = out;
    float* cdot1 = out + (size_t)NTOK * NCH;

    hipMemsetAsync(counts, 0, 256, stream);
    prep_kernel<<<8512, 256, 0, stream>>>(x, x_hi, x_lo, gw1, w1cat,
                                          p2_w, p4_w, rg_u, fl_dw, w1cheap,
                                          dfc_w, dfc_wt, dproj_w, dpj_wt,
                                          sfc_w, sfc_wt, sproj_w, spj_wt);
    gate_partial_kernel<<<dim3(GH / 64, NTOK / 64, 2), 256, 0, stream>>>(
        x_hi, x_lo, w1cat, w1cheap, hp0, hp1, cdot0, cdot1);
    gate_finalize_kernel<<<NTOK / 32, 256, 0, stream>>>(
        hp0, hp1, gb1, gw2, gb2, ebias, pm_alpha, cdot0, cdot1,
        p2_alpha, p2_b, p4_alpha, p4_b, rg_b, fl_db,
        scale, counts, tlist, eid, gvec);
    // y: 32 x 64-row tiles = 2048 rows (mean+20sigma of fixed multinomial counts)
    moe_gemm1_kernel<<<dim3(32, 32, 2), 256, 0, stream>>>(
        x_hi, dfc_wt, sfc_wt, dfc_b, sfc_b, counts, tlist, h1, h2);
    gemm2_cheap_kernel<<<1024 + NTOK, 256, 0, stream>>>(
        h1, h2, dpj_wt, spj_wt, dproj_b, sproj_b, counts, tlist, scale,
        x, eid, gvec,
        p2_v, p2_bias, p4_v, p4_bias,
        rg_a, rg_bias, fl_uw, fl_ub, out);
    (void)in_sizes; (void)n_in; (void)out_size; (void)ws_size;
}

// Round 2
// 290.839 us; speedup vs baseline: 1.0453x; 1.0453x over previous
//
#include <hip/hip_runtime.h>
#include <math.h>

// Top-1 MoE, 6-dispatch pipeline.
//   memset -> prep -> gate_partial -> gate_finalize -> gemm1 -> gemm2+cheap.
// r13: cheap-expert dots ride gate_partial's MFMA (gvec); cheap blocks stream.
// r14: XCD-chunked swizzle on all three MFMA GEMMs. rocprof showed
// gate_partial FETCH=132MB vs 33MB unique (4x A re-fetch: the 4 n-blocks of a
// strip land on 4 different XCD L2s). Remap bid -> (xcd=bid&7, slot=bid>>3),
// work = strip(xcd-strided for balance) x n(consecutive slots, co-resident on
// one XCD) so A-strips are L2-served after the first miss. Same for gemm1
// (32x A re-read) and gemm2's GEMM half (16x).

#define E 1024
#define GH 256
#define NEXP 6
#define NTOK 8192
#define NCH 24   // cheap-dot cols: 2 p2 + 4 p4 + 1 rg + 16 film + 1 pad

typedef __attribute__((ext_vector_type(8))) short bf16x8;
typedef __attribute__((ext_vector_type(4))) float f32x4;

__device__ __forceinline__ float gelu_erf(float v) {
    return 0.5f * v * (1.0f + erff(v * 0.70710678118654752440f));
}

__device__ __forceinline__ unsigned short f2bf(float f) {
    union { float f; unsigned u; } c; c.f = f;
    unsigned u = c.u;
    u += 0x7fffu + ((u >> 16) & 1u);   // RNE
    return (unsigned short)(u >> 16);
}

__device__ __forceinline__ float bf2f(unsigned short h) {
    union { unsigned u; float f; } c; c.u = ((unsigned)h) << 16;
    return c.f;
}

// LDS tile addressing (ushort units): row stride 32 (=64B), k-group XOR swizzle.
__device__ __forceinline__ int ldso(int row, int q) {
    return row * 32 + ((q ^ ((row >> 1) & 3)) << 3);
}

// ---------------- prep: convert + all transposes, one kernel ----------------
__global__ __launch_bounds__(256)
void prep_kernel(const float* __restrict__ x, unsigned short* __restrict__ xh,
                 unsigned short* __restrict__ xl,
                 const float* __restrict__ gw1, unsigned short* __restrict__ w1cat,
                 const float* __restrict__ p2_w, const float* __restrict__ p4_w,
                 const float* __restrict__ rg_u, const float* __restrict__ fl_dw,
                 unsigned short* __restrict__ w1cheap,
                 const float* __restrict__ dfc_w, unsigned short* __restrict__ dfc_wt,
                 const float* __restrict__ dproj_w, unsigned short* __restrict__ dpj_wt,
                 const float* __restrict__ sfc_w, unsigned short* __restrict__ sfc_wt,
                 const float* __restrict__ sproj_w, unsigned short* __restrict__ spj_wt) {
    __shared__ float tile[32][33];
    const int tid = threadIdx.x;
    const int tx = tid & 31, ty = tid >> 5;
    int b = blockIdx.x;
    if (b < 2048) {                       // x -> x_hi + x_lo
        const int n4 = NTOK * E / 4;
        for (int i = b * 256 + tid; i < n4; i += 2048 * 256) {
            float4 v = reinterpret_cast<const float4*>(x)[i];
            ushort4 h, l;
            h.x = f2bf(v.x); l.x = f2bf(v.x - bf2f(h.x));
            h.y = f2bf(v.y); l.y = f2bf(v.y - bf2f(h.y));
            h.z = f2bf(v.z); l.z = f2bf(v.z - bf2f(h.z));
            h.w = f2bf(v.w); l.w = f2bf(v.w - bf2f(h.w));
            reinterpret_cast<ushort4*>(xh)[i] = h;
            reinterpret_cast<ushort4*>(xl)[i] = l;
        }
        return;
    }
    b -= 2048;
    if (b < 256) {                        // gw1 [E][GH] -> w1cat [GH][hi|lo]
        const int c0 = (b & 7) * 32, r0 = (b >> 3) * 32;
#pragma unroll
        for (int i = 0; i < 4; ++i)
            tile[ty + i * 8][tx] = gw1[(size_t)(r0 + ty + i * 8) * GH + c0 + tx];
        __syncthreads();
#pragma unroll
        for (int i = 0; i < 4; ++i) {
            float v = tile[tx][ty + i * 8];
            unsigned short h = f2bf(v);
            size_t row = (size_t)(c0 + ty + i * 8) * 2048;
            w1cat[row + r0 + tx] = h;
            w1cat[row + 1024 + r0 + tx] = f2bf(v - bf2f(h));
        }
        return;
    }
    b -= 256;
    if (b < 64) {                         // cheap-dot weights -> w1cheap [64][hi|lo]
        const int r = b;
        const int k4 = tid * 4;
        float4 v = {0.f, 0.f, 0.f, 0.f};
        if (r < 2)       v = *reinterpret_cast<const float4*>(&p2_w[r * E + k4]);
        else if (r < 6)  v = *reinterpret_cast<const float4*>(&p4_w[(r - 2) * E + k4]);
        else if (r == 6) v = *reinterpret_cast<const float4*>(&rg_u[k4]);
        else if (r < 23) {
            const int j = r - 7;          // fl_dw is [E][16]: gather column j
            v.x = fl_dw[(k4 + 0) * 16 + j];
            v.y = fl_dw[(k4 + 1) * 16 + j];
            v.z = fl_dw[(k4 + 2) * 16 + j];
            v.w = fl_dw[(k4 + 3) * 16 + j];
        }
        ushort4 h, l;
        h.x = f2bf(v.x); l.x = f2bf(v.x - bf2f(h.x));
        h.y = f2bf(v.y); l.y = f2bf(v.y - bf2f(h.y));
        h.z = f2bf(v.z); l.z = f2bf(v.z - bf2f(h.z));
        h.w = f2bf(v.w); l.w = f2bf(v.w - bf2f(h.w));
        *reinterpret_cast<ushort4*>(&w1cheap[r * 2048 + k4]) = h;
        *reinterpret_cast<ushort4*>(&w1cheap[r * 2048 + 1024 + k4]) = l;
        return;
    }
    b -= 64;
    const float* src; unsigned short* dst; int R, C, nbx;
    if (b < 2048)      { src = dfc_w;   dst = dfc_wt; R = 1024; C = 2048; nbx = 64; }
    else if (b < 4096) { src = dproj_w; dst = dpj_wt; R = 2048; C = 1024; nbx = 32; b -= 2048; }
    else if (b < 5120) { src = sfc_w;   dst = sfc_wt; R = 1024; C = 1024; nbx = 32; b -= 4096; }
    else               { src = sproj_w; dst = spj_wt; R = 1024; C = 1024; nbx = 32; b -= 5120; }
    const int c0 = (b % nbx) * 32, r0 = (b / nbx) * 32;
#pragma unroll
    for (int i = 0; i < 4; ++i)
        tile[ty + i * 8][tx] = src[(size_t)(r0 + ty + i * 8) * C + c0 + tx];
    __syncthreads();
#pragma unroll
    for (int i = 0; i < 4; ++i)
        dst[(size_t)(c0 + ty + i * 8) * R + r0 + tx] = f2bf(tile[tx][ty + i * 8]);
}

// ------ gate partial GEMM: hp_z = A_z @ w1cat, 64x64 tiles, LDS dbuf -------
// 1D grid 1024 blocks, XCD-chunked: xcd=bid&7, slot=bid>>3; n-tile fastest in
// slot (4 n-blocks of a strip co-resident on one XCD -> A L2-reuse);
// strip = xcd + 8*j (XCD-strided for balance). 4 waves of 32x32.
// n-tile-0 blocks additionally compute the 64x24 cheap-dot tile (A @ w1cheap^T)
// with cheap-B fragments loaded straight from L2 (256KB, fully cached).
__global__ __launch_bounds__(256)
void gate_partial_kernel(const unsigned short* __restrict__ xh,
                         const unsigned short* __restrict__ xl,
                         const unsigned short* __restrict__ w1cat,
                         const unsigned short* __restrict__ w1cheap,
                         float* __restrict__ hp0, float* __restrict__ hp1,
                         float* __restrict__ cdot0, float* __restrict__ cdot1) {
    __shared__ __align__(16) unsigned short As[2][64 * 32];
    __shared__ __align__(16) unsigned short Bs[2][64 * 32];
    const int tid = threadIdx.x;
    // --- XCD-chunked swizzle: bid -> (strip, nx), n fastest within an XCD ---
    const int bid = blockIdx.x;
    const int xcd = bid & 7, slot = bid >> 3;          // slot in [0,128)
    const int nx = slot & 3;
    const int strip = xcd + 8 * (slot >> 2);           // [0,256), XCD-strided
    const int z = strip & 1;
    const int t0 = (strip >> 1) * 64, n0 = nx * 64;
    const unsigned short* A = z ? xl : xh;
    float* hp = z ? hp1 : hp0;
    float* cd = z ? cdot1 : cdot0;

    const int lane = tid & 63, wv = tid >> 6;
    const int wm = (wv & 1) * 32, wn = (wv >> 1) * 32;
    const int lm = lane & 15, q = lane >> 4;
    const int r0 = tid >> 2, gsl = tid & 3;
    const int g = gsl ^ ((r0 >> 1) & 3);
    const int so = r0 * 32 + gsl * 8;

    const unsigned short* pa = A + (size_t)(t0 + r0) * E + g * 8;
    const unsigned short* pb = w1cat + (size_t)(n0 + r0) * 2048 + g * 8;

    // cheap tile: wave wv covers rows wm..wm+31 x cheap-cols tc*16..tc*16+15
    const bool docheap = (nx == 0);
    const int tc = wv >> 1;
    const unsigned short* pcw = w1cheap + (size_t)(tc * 16 + lm) * 2048 + q * 8;

    f32x4 acc[2][2];
#pragma unroll
    for (int s = 0; s < 2; ++s)
#pragma unroll
        for (int t = 0; t < 2; ++t) acc[s][t] = (f32x4){0.f, 0.f, 0.f, 0.f};
    f32x4 accC[2];
    accC[0] = (f32x4){0.f, 0.f, 0.f, 0.f};
    accC[1] = (f32x4){0.f, 0.f, 0.f, 0.f};

    bf16x8 ra = *(const bf16x8*)(pa);
    bf16x8 rb = *(const bf16x8*)(pb);
    bf16x8 cfv, cfn;
    if (docheap) cfv = *(const bf16x8*)(pcw);
    *(bf16x8*)&As[0][so] = ra;
    *(bf16x8*)&Bs[0][so] = rb;

    int cur = 0, k0 = 0;
    while (true) {
        __syncthreads();                      // buf[cur] writes + prev reads done
        const int kn = k0 + 32;
        if (kn < 2048) {
            ra = *(const bf16x8*)(pa + (kn & 1023));
            rb = *(const bf16x8*)(pb + kn);
            if (docheap) cfn = *(const bf16x8*)(pcw + kn);
        }
        bf16x8 af[2], bf[2];
#pragma unroll
        for (int s = 0; s < 2; ++s) af[s] = *(const bf16x8*)&As[cur][ldso(wm + s * 16 + lm, q)];
#pragma unroll
        for (int t = 0; t < 2; ++t) bf[t] = *(const bf16x8*)&Bs[cur][ldso(wn + t * 16 + lm, q)];
#pragma unroll
        for (int s = 0; s < 2; ++s)
#pragma unroll
            for (int t = 0; t < 2; ++t)
                acc[s][t] = __builtin_amdgcn_mfma_f32_16x16x32_bf16(af[s], bf[t], acc[s][t], 0, 0, 0);
        if (docheap) {
            accC[0] = __builtin_amdgcn_mfma_f32_16x16x32_bf16(af[0], cfv, accC[0], 0, 0, 0);
            accC[1] = __builtin_amdgcn_mfma_f32_16x16x32_bf16(af[1], cfv, accC[1], 0, 0, 0);
        }
        if (kn >= 2048) break;
        *(bf16x8*)&As[cur ^ 1][so] = ra;
        *(bf16x8*)&Bs[cur ^ 1][so] = rb;
        cfv = cfn;
        cur ^= 1; k0 = kn;
    }
#pragma unroll
    for (int s = 0; s < 2; ++s)
#pragma unroll
        for (int t = 0; t < 2; ++t)
#pragma unroll
            for (int rg = 0; rg < 4; ++rg) {
                int rl = wm + s * 16 + q * 4 + rg;
                int c  = wn + t * 16 + lm;
                hp[(size_t)(t0 + rl) * GH + n0 + c] = acc[s][t][rg];
            }
    if (docheap) {
        const int c = tc * 16 + lm;
        if (c < NCH) {
#pragma unroll
            for (int s = 0; s < 2; ++s)
#pragma unroll
                for (int rg = 0; rg < 4; ++rg) {
                    int rl = wm + s * 16 + q * 4 + rg;
                    cd[(size_t)(t0 + rl) * NCH + c] = accC[s][rg];
                }
        }
    }
}

// ------- finalize: h=gelu(hp0+hp1+gb1); logits=h@gw2; softmax/argmax --------
// Also converts summed cheap dots into per-token gate scalars gvec[NCH].
__global__ __launch_bounds__(256)
void gate_finalize_kernel(const float* __restrict__ hp0, const float* __restrict__ hp1,
                          const float* __restrict__ gb1, const float* __restrict__ gw2,
                          const float* __restrict__ gb2, const float* __restrict__ ebias,
                          const float* __restrict__ pm_alpha,
                          const float* __restrict__ cdot0, const float* __restrict__ cdot1,
                          const float* __restrict__ p2_alpha, const float* __restrict__ p2_b,
                          const float* __restrict__ p4_alpha, const float* __restrict__ p4_b,
                          const float* __restrict__ rg_b, const float* __restrict__ fl_db,
                          float* __restrict__ scale, int* __restrict__ counts,
                          int* __restrict__ tlist, int* __restrict__ eid,
                          float* __restrict__ gvec) {
    __shared__ float hs[32][264];
    __shared__ float g2s[GH * NEXP];
    __shared__ int tokexp[32];
    const int tid = threadIdx.x;
    const int t0 = blockIdx.x * 32;
    for (int i = tid; i < GH * NEXP; i += 256) g2s[i] = gw2[i];
#pragma unroll
    for (int i = 0; i < 8; ++i) {
        int f4 = i * 256 + tid;
        int row = f4 >> 6, c4 = (f4 & 63) * 4;
        size_t base = (size_t)(t0 + row) * GH + c4;
        float4 a = *reinterpret_cast<const float4*>(&hp0[base]);
        float4 b = *reinterpret_cast<const float4*>(&hp1[base]);
        float4 o;
        o.x = gelu_erf(a.x + b.x + gb1[c4 + 0]);
        o.y = gelu_erf(a.y + b.y + gb1[c4 + 1]);
        o.z = gelu_erf(a.z + b.z + gb1[c4 + 2]);
        o.w = gelu_erf(a.w + b.w + gb1[c4 + 3]);
        *reinterpret_cast<float4*>(&hs[row][c4]) = o;
    }
    __syncthreads();
    const int t = tid >> 3, j = tid & 7;
    float p[NEXP] = {0.f, 0.f, 0.f, 0.f, 0.f, 0.f};
#pragma unroll 8
    for (int kk = 0; kk < 32; ++kk) {
        int k = j + kk * 8;
        float hv = hs[t][k];
        const float* gr = &g2s[k * NEXP];
#pragma unroll
        for (int m = 0; m < NEXP; ++m) p[m] += hv * gr[m];
    }
#pragma unroll
    for (int m = 0; m < NEXP; ++m) {
        p[m] += __shfl_xor(p[m], 4, 64);
        p[m] += __shfl_xor(p[m], 2, 64);
        p[m] += __shfl_xor(p[m], 1, 64);
    }
    if (j == 0) {
        float L[NEXP];
#pragma unroll
        for (int m = 0; m < NEXP; ++m) L[m] = p[m] + gb2[m] + ebias[m];
        float mx = L[0]; int am = 0;
#pragma unroll
        for (int m = 1; m < NEXP; ++m) { if (L[m] > mx) { mx = L[m]; am = m; } }
        float S = 0.f;
#pragma unroll
        for (int m = 0; m < NEXP; ++m) S += expf(L[m] - mx);
        float pt = 1.f / S;
        scale[t0 + t] = pm_alpha[0] * (pt / (pt + 1e-9f));
        eid[t0 + t] = am;
        tokexp[t] = am;
    }
    __syncthreads();
    if (tid < NEXP) {
        const int e = tid;
        int cnt = 0;
#pragma unroll
        for (int i = 0; i < 32; ++i) cnt += (tokexp[i] == e);
        if (cnt) {
            int base = atomicAdd(&counts[e], cnt);
            int pos = 0;
#pragma unroll
            for (int i = 0; i < 32; ++i)
                if (tokexp[i] == e) tlist[e * NTOK + base + (pos++)] = t0 + i;
        }
    }
    // ---- per-token cheap-gate scalars (independent of the above) ----
    for (int i = tid; i < 32 * NCH; i += 256) {
        const int tt = i / NCH, slot = i - tt * NCH;
        const int tok = t0 + tt;
        float s = cdot0[(size_t)tok * NCH + slot] + cdot1[(size_t)tok * NCH + slot];
        float val;
        if (slot < 2)       val = p2_alpha[slot] * gelu_erf(s + p2_b[slot]);
        else if (slot < 6)  val = p4_alpha[slot - 2] * gelu_erf(s + p4_b[slot - 2]);
        else if (slot == 6) val = 1.f / (1.f + expf(-(s + rg_b[0])));
        else if (slot < 23) val = gelu_erf(s + fl_db[slot - 7]);
        else                val = 0.f;
        gvec[(size_t)tok * NCH + slot] = val;
    }
}

// ---------------- GEMM1: gather x_hi -> gelu -> packed bf16 h ---------------
// 1D grid 2048, XCD-chunked (n fastest, strip = xcd + 8*j). 64x64 tiles,
// 4 waves of 32x32, LDS double buffer.
__global__ __launch_bounds__(256)
void moe_gemm1_kernel(const unsigned short* __restrict__ xh,
                      const unsigned short* __restrict__ B0, const unsigned short* __restrict__ B1,
                      const float* __restrict__ bias0, const float* __restrict__ bias1,
                      const int* __restrict__ counts, const int* __restrict__ tlist,
                      unsigned short* __restrict__ H0, unsigned short* __restrict__ H1) {
    const int bid = blockIdx.x;
    const int xcd = bid & 7, slot = bid >> 3;          // slot in [0,256)
    const int nx = slot & 31;
    const int strip = xcd + 8 * (slot >> 5);           // [0,64), XCD-strided
    const int z = strip & 1;
    const int N = z ? 1024 : 2048;
    const int cnt = counts[z];
    const int i0 = (strip >> 1) * 64;
    const int n0 = nx * 64;
    if (i0 >= cnt || n0 >= N) return;
    const unsigned short* Bz = z ? B1 : B0;
    const float* bias = z ? bias1 : bias0;

    __shared__ __align__(16) unsigned short As[2][64 * 32];
    __shared__ __align__(16) unsigned short Bs[2][64 * 32];
    __shared__ int toks[64];
    const int tid = threadIdx.x;
    if (tid < 64) toks[tid] = tlist[z * NTOK + min(i0 + tid, cnt - 1)];
    __syncthreads();

    const int lane = tid & 63, wv = tid >> 6;
    const int wm = (wv & 1) * 32, wn = (wv >> 1) * 32;
    const int lm = lane & 15, q = lane >> 4;
    const int r0 = tid >> 2, gsl = tid & 3;
    const int g = gsl ^ ((r0 >> 1) & 3);
    const int so = r0 * 32 + gsl * 8;

    const unsigned short* pa = xh + (size_t)toks[r0] * E + g * 8;
    const unsigned short* pb = Bz + (size_t)(n0 + r0) * E + g * 8;

    f32x4 acc[2][2];
#pragma unroll
    for (int s = 0; s < 2; ++s)
#pragma unroll
        for (int t = 0; t < 2; ++t) acc[s][t] = (f32x4){0.f, 0.f, 0.f, 0.f};

    bf16x8 ra = *(const bf16x8*)(pa);
    bf16x8 rb = *(const bf16x8*)(pb);
    *(bf16x8*)&As[0][so] = ra;
    *(bf16x8*)&Bs[0][so] = rb;

    int cur = 0, k0 = 0;
    while (true) {
        __syncthreads();
        const int kn = k0 + 32;
        if (kn < E) {
            ra = *(const bf16x8*)(pa + kn);
            rb = *(const bf16x8*)(pb + kn);
        }
        bf16x8 af[2], bf[2];
#pragma unroll
        for (int s = 0; s < 2; ++s) af[s] = *(const bf16x8*)&As[cur][ldso(wm + s * 16 + lm, q)];
#pragma unroll
        for (int t = 0; t < 2; ++t) bf[t] = *(const bf16x8*)&Bs[cur][ldso(wn + t * 16 + lm, q)];
#pragma unroll
        for (int s = 0; s < 2; ++s)
#pragma unroll
            for (int t = 0; t < 2; ++t)
                acc[s][t] = __builtin_amdgcn_mfma_f32_16x16x32_bf16(af[s], bf[t], acc[s][t], 0, 0, 0);
        if (kn >= E) break;
        *(bf16x8*)&As[cur ^ 1][so] = ra;
        *(bf16x8*)&Bs[cur ^ 1][so] = rb;
        cur ^= 1; k0 = kn;
    }
    unsigned short* Hz = z ? H1 : H0;
#pragma unroll
    for (int s = 0; s < 2; ++s)
#pragma unroll
        for (int t = 0; t < 2; ++t)
#pragma unroll
            for (int rg = 0; rg < 4; ++rg) {
                int rl = wm + s * 16 + q * 4 + rg;
                int gc = n0 + wn + t * 16 + lm;
                float v = acc[s][t][rg] + bias[gc];
                Hz[(size_t)(i0 + rl) * N + gc] = f2bf(gelu_erf(v));
            }
}

// -------- fused GEMM2 (experts 0/1 down-proj) + cheap experts (2..5) --------
// blocks [0,1024): gemm2 64x64 tile, LDS dbuf, XCD-chunked (n fastest).
// blocks [1024, 1024+NTOK): cheap token b-1024 -- pure streaming via gvec
// (dots precomputed by gate_partial; no reductions, no syncthreads).
__global__ __launch_bounds__(256)
void gemm2_cheap_kernel(const unsigned short* __restrict__ h1, const unsigned short* __restrict__ h2,
                        const unsigned short* __restrict__ dpj, const unsigned short* __restrict__ spj,
                        const float* __restrict__ dproj_b, const float* __restrict__ sproj_b,
                        const int* __restrict__ counts, const int* __restrict__ tlist,
                        const float* __restrict__ scale,
                        const float* __restrict__ x, const int* __restrict__ eid,
                        const float* __restrict__ gvec,
                        const float* __restrict__ p2_v, const float* __restrict__ p2_bias,
                        const float* __restrict__ p4_v, const float* __restrict__ p4_bias,
                        const float* __restrict__ rg_a, const float* __restrict__ rg_bias,
                        const float* __restrict__ fl_uw, const float* __restrict__ fl_ub,
                        float* __restrict__ out) {
    __shared__ __align__(16) char smem[2 * 64 * 32 * 2 * 2 + 64 * 4];  // 16.6 KB
    const int tid = threadIdx.x;
    const int bb = blockIdx.x;
    const int lane = tid & 63;

    if (bb < 1024) {
        const int xcd = bb & 7, slot = bb >> 3;        // slot in [0,128)
        const int nx = slot & 15;
        const int strip = xcd + 8 * (slot >> 4);       // [0,64), XCD-strided
        const int z = strip & 1;
        const int n0 = nx * 64;
        const int i0 = (strip >> 1) * 64;
        const int K = z ? 1024 : 2048;
        const int cnt = counts[z];
        if (i0 >= cnt) return;
        const int rows = min(64, cnt - i0);
        const unsigned short* Az = z ? h2 : h1;
        const unsigned short* Bz = z ? spj : dpj;
        const float* bias = z ? sproj_b : dproj_b;

        unsigned short (*As)[64 * 32] = (unsigned short (*)[64 * 32])smem;
        unsigned short (*Bs)[64 * 32] = (unsigned short (*)[64 * 32])(smem + 2 * 64 * 32 * 2);
        int* toks = (int*)(smem + 2 * 64 * 32 * 2 * 2);
        if (tid < 64) toks[tid] = tlist[z * NTOK + min(i0 + tid, cnt - 1)];
        __syncthreads();

        const int wv = tid >> 6;
        const int wm = (wv & 1) * 32, wn = (wv >> 1) * 32;
        const int lm = lane & 15, q = lane >> 4;
        const int r0 = tid >> 2, gsl = tid & 3;
        const int g = gsl ^ ((r0 >> 1) & 3);
        const int so = r0 * 32 + gsl * 8;

        const unsigned short* pa = Az + (size_t)(i0 + r0) * K + g * 8;
        const unsigned short* pb = Bz + (size_t)(n0 + r0) * K + g * 8;

        f32x4 acc[2][2];
#pragma unroll
        for (int s = 0; s < 2; ++s)
#pragma unroll
            for (int t = 0; t < 2; ++t) acc[s][t] = (f32x4){0.f, 0.f, 0.f, 0.f};

        bf16x8 ra = *(const bf16x8*)(pa);
        bf16x8 rb = *(const bf16x8*)(pb);
        *(bf16x8*)&As[0][so] = ra;
        *(bf16x8*)&Bs[0][so] = rb;

        int cur = 0, k0 = 0;
        while (true) {
            __syncthreads();
            const int kn = k0 + 32;
            if (kn < K) {
                ra = *(const bf16x8*)(pa + kn);
                rb = *(const bf16x8*)(pb + kn);
            }
            bf16x8 af[2], bf[2];
#pragma unroll
            for (int s = 0; s < 2; ++s) af[s] = *(const bf16x8*)&As[cur][ldso(wm + s * 16 + lm, q)];
#pragma unroll
            for (int t = 0; t < 2; ++t) bf[t] = *(const bf16x8*)&Bs[cur][ldso(wn + t * 16 + lm, q)];
#pragma unroll
            for (int s = 0; s < 2; ++s)
#pragma unroll
                for (int t = 0; t < 2; ++t)
                    acc[s][t] = __builtin_amdgcn_mfma_f32_16x16x32_bf16(af[s], bf[t], acc[s][t], 0, 0, 0);
            if (kn >= K) break;
            *(bf16x8*)&As[cur ^ 1][so] = ra;
            *(bf16x8*)&Bs[cur ^ 1][so] = rb;
            cur ^= 1; k0 = kn;
        }
#pragma unroll
        for (int s = 0; s < 2; ++s)
#pragma unroll
            for (int t = 0; t < 2; ++t)
#pragma unroll
                for (int rg = 0; rg < 4; ++rg) {
                    int rl = wm + s * 16 + q * 4 + rg;
                    if (rl < rows) {
                        int gc = n0 + wn + t * 16 + lm;
                        int tok = toks[rl];
                        out[(size_t)tok * E + gc] = scale[tok] * (acc[s][t][rg] + bias[gc]);
                    }
                }
        return;
    }

    // ---- cheap experts: one block per token, pure streaming via gvec ----
    const int tok = bb - 1024;
    const int e = eid[tok];
    if (e < 2) return;
    const float sc = scale[tok];
    const int k4 = tid * 4;
    const float* gv = &gvec[(size_t)tok * NCH];
    float4 o;

    if (e == 2) {
        const float g0 = gv[0], g1 = gv[1];
        float4 b0 = *reinterpret_cast<const float4*>(&p2_bias[k4]);
        float4 v0 = *reinterpret_cast<const float4*>(&p2_v[k4]);
        float4 v1 = *reinterpret_cast<const float4*>(&p2_v[E + k4]);
        o.x = b0.x + g0 * v0.x + g1 * v1.x;
        o.y = b0.y + g0 * v0.y + g1 * v1.y;
        o.z = b0.z + g0 * v0.z + g1 * v1.z;
        o.w = b0.w + g0 * v0.w + g1 * v1.w;
    } else if (e == 3) {
        o = *reinterpret_cast<const float4*>(&p4_bias[k4]);
#pragma unroll
        for (int j = 0; j < 4; ++j) {
            const float gj = gv[2 + j];
            float4 vv = *reinterpret_cast<const float4*>(&p4_v[j * E + k4]);
            o.x += gj * vv.x; o.y += gj * vv.y; o.z += gj * vv.z; o.w += gj * vv.w;
        }
    } else if (e == 4) {
        const float sg = gv[6];
        float4 xv = *reinterpret_cast<const float4*>(&x[(size_t)tok * E + k4]);
        float4 av = *reinterpret_cast<const float4*>(&rg_a[k4]);
        float4 bv = *reinterpret_cast<const float4*>(&rg_bias[k4]);
        o.x = sg * xv.x * av.x + bv.x;
        o.y = sg * xv.y * av.y + bv.y;
        o.z = sg * xv.z * av.z + bv.z;
        o.w = sg * xv.w * av.w + bv.w;
    } else {  // FiLM
        float4 xv = *reinterpret_cast<const float4*>(&x[(size_t)tok * E + k4]);
        float4 ga = *reinterpret_cast<const float4*>(&fl_ub[k4]);
        float4 be = *reinterpret_cast<const float4*>(&fl_ub[E + k4]);
#pragma unroll
        for (int j = 0; j < 16; ++j) {
            const float tj = gv[7 + j];
            float4 ug = *reinterpret_cast<const float4*>(&fl_uw[(size_t)j * 2 * E + k4]);
            float4 ub = *reinterpret_cast<const float4*>(&fl_uw[(size_t)j * 2 * E + E + k4]);
            ga.x += tj * ug.x; ga.y += tj * ug.y; ga.z += tj * ug.z; ga.w += tj * ug.w;
            be.x += tj * ub.x; be.y += tj * ub.y; be.z += tj * ub.z; be.w += tj * ub.w;
        }
        o.x = ga.x * xv.x + be.x;
        o.y = ga.y * xv.y + be.y;
        o.z = ga.z * xv.z + be.z;
        o.w = ga.w * xv.w + be.w;
    }
    o.x *= sc; o.y *= sc; o.z *= sc; o.w *= sc;
    *reinterpret_cast<float4*>(&out[(size_t)tok * E + k4]) = o;
}

extern "C" void kernel_launch(void* const* d_in, const int* in_sizes, int n_in,
                              void* d_out, int out_size, void* d_ws, size_t ws_size,
                              hipStream_t stream) {
    const float* x        = (const float*)d_in[0];
    const float* gw1      = (const float*)d_in[1];
    const float* gb1      = (const float*)d_in[2];
    const float* gw2      = (const float*)d_in[3];
    const float* gb2      = (const float*)d_in[4];
    const float* ebias    = (const float*)d_in[5];
    const float* pm_alpha = (const float*)d_in[6];
    const float* dfc_w    = (const float*)d_in[7];
    const float* dfc_b    = (const float*)d_in[8];
    const float* dproj_w  = (const float*)d_in[9];
    const float* dproj_b  = (const float*)d_in[10];
    const float* sfc_w    = (const float*)d_in[11];
    const float* sfc_b    = (const float*)d_in[12];
    const float* sproj_w  = (const float*)d_in[13];
    const float* sproj_b  = (const float*)d_in[14];
    const float* p2_w     = (const float*)d_in[15];
    const float* p2_v     = (const float*)d_in[16];
    const float* p2_alpha = (const float*)d_in[17];
    const float* p2_b     = (const float*)d_in[18];
    const float* p2_bias  = (const float*)d_in[19];
    const float* p4_w     = (const float*)d_in[20];
    const float* p4_v     = (const float*)d_in[21];
    const float* p4_alpha = (const float*)d_in[22];
    const float* p4_b     = (const float*)d_in[23];
    const float* p4_bias  = (const float*)d_in[24];
    const float* rg_u     = (const float*)d_in[25];
    const float* rg_a     = (const float*)d_in[26];
    const float* rg_b     = (const float*)d_in[27];
    const float* rg_bias  = (const float*)d_in[28];
    const float* fl_dw    = (const float*)d_in[29];
    const float* fl_db    = (const float*)d_in[30];
    const float* fl_uw    = (const float*)d_in[31];
    const float* fl_ub    = (const float*)d_in[32];
    float* out = (float*)d_out;

    char* ws = (char*)d_ws;
    size_t off = 0;
    int*            counts = (int*)(ws + off);            off += 256;
    float*          scale  = (float*)(ws + off);          off += (size_t)NTOK * 4;
    int*            tlist  = (int*)(ws + off);            off += (size_t)NEXP * NTOK * 4;
    int*            eid    = (int*)(ws + off);            off += (size_t)NTOK * 4;
    float*          gvec   = (float*)(ws + off);          off += (size_t)NTOK * NCH * 4;
    unsigned short* w1cheap= (unsigned short*)(ws + off); off += (size_t)64 * 2048 * 2;
    unsigned short* w1cat  = (unsigned short*)(ws + off); off += (size_t)GH * 2048 * 2;
    unsigned short* dfc_wt = (unsigned short*)(ws + off); off += (size_t)2048 * 1024 * 2;
    unsigned short* dpj_wt = (unsigned short*)(ws + off); off += (size_t)1024 * 2048 * 2;
    unsigned short* sfc_wt = (unsigned short*)(ws + off); off += (size_t)1024 * 1024 * 2;
    unsigned short* spj_wt = (unsigned short*)(ws + off); off += (size_t)1024 * 1024 * 2;
    unsigned short* x_hi   = (unsigned short*)(ws + off); off += (size_t)NTOK * E * 2;
    // Union region (32 MB): gate phase {x_lo, hp0, hp1} then expert phase {h1, h2}
    char* U = ws + off;
    unsigned short* x_lo = (unsigned short*)U;                              // 16 MB
    float*          hp0  = (float*)(U + (size_t)16 * 1024 * 1024);          // 8 MB
    float*          hp1  = (float*)(U + (size_t)24 * 1024 * 1024);          // 8 MB
    unsigned short* h1   = (unsigned short*)U;                              // 16 MB (2048 x 2048)
    unsigned short* h2   = (unsigned short*)(U + (size_t)16 * 1024 * 1024); // 8 MB (2048 x 1024)
    // cheap-dot partials live in d_out (dead until gemm2_cheap rewrites it)
    float* cdot0 = out;
    float* cdot1 = out + (size_t)NTOK * NCH;

    hipMemsetAsync(counts, 0, 256, stream);
    prep_kernel<<<8512, 256, 0, stream>>>(x, x_hi, x_lo, gw1, w1cat,
                                          p2_w, p4_w, rg_u, fl_dw, w1cheap,
                                          dfc_w, dfc_wt, dproj_w, dpj_wt,
                                          sfc_w, sfc_wt, sproj_w, spj_wt);
    gate_partial_kernel<<<1024, 256, 0, stream>>>(
        x_hi, x_lo, w1cat, w1cheap, hp0, hp1, cdot0, cdot1);
    gate_finalize_kernel<<<NTOK / 32, 256, 0, stream>>>(
        hp0, hp1, gb1, gw2, gb2, ebias, pm_alpha, cdot0, cdot1,
        p2_alpha, p2_b, p4_alpha, p4_b, rg_b, fl_db,
        scale, counts, tlist, eid, gvec);
    // y: 32 x 64-row tiles = 2048 rows (mean+20sigma of fixed multinomial counts)
    moe_gemm1_kernel<<<2048, 256, 0, stream>>>(
        x_hi, dfc_wt, sfc_wt, dfc_b, sfc_b, counts, tlist, h1, h2);
    gemm2_cheap_kernel<<<1024 + NTOK, 256, 0, stream>>>(
        h1, h2, dpj_wt, spj_wt, dproj_b, sproj_b, counts, tlist, scale,
        x, eid, gvec,
        p2_v, p2_bias, p4_v, p4_bias,
        rg_a, rg_bias, fl_uw, fl_ub, out);
    (void)in_sizes; (void)n_in; (void)out_size; (void)ws_size;
}